// Round 11
// baseline (314993.433 us; speedup 1.0000x reference)
//
#include <hip/hip_runtime.h>
#include <math.h>

#define NS 512          // states
#define NI 32           // inputs
#define NO 16           // outputs
#define TT 4096         // time points
#define NSTEP (TT - 1)  // 4095 integration steps
#define TPB 1024        // 16 waves/CU: halves the CU count at same VGPR economy
#define NBLK_TOT 64     // launched blocks; 2 co-XCD blocks win the election
#define GK 2            // group size: 2 CUs x 256 rows (a[16][8] preserved)

// ---- control plane: d_ws (re-poisoned each iteration; agent-scope proven) ----
#define W_CNT   1024
#define W_WIN   1200
#define W_DEC   1280
#define W_SINK  1320
#define W_DONE  1336
#define W_NONCE 1352
#define POISON64 0xAAAAAAAAAAAAAAAAull
#define H1V 0x1111000011110001ull
#define H2V 0x2222000022220002ull
#define DONEV 0x600D600D600D600Dull
#define CAP_ELECT  10000000ll    // 0.1 s @ 100 MHz s_memrealtime
#define CAP_HAND    1000000ll    // 10 ms
#define CAP_DEC    50000000ll    // 0.5 s
#define CAP_POLL   30000000ll    // 0.3 s failsafe
#define CAP_HEAT   30000000ll    // 0.3 s failsafe for heater blocks

// ---- data plane: module-scope device global (coarse VRAM). ----
// Primitive matrix (R0-R10): plain load = stale L1; sc0/nt load = MALL;
// atomic add0 = the only L2-served read; publish = unscoped atomic swap
// (TCC-executed, L2-resident, fire-and-forget safe). R10 = 48.1ms @ GK=4.
// R10 verdict: line-spread+LDS-bypass bought 3% -> exchange is RTT+skew
// bound, not contention bound. R11: GK=2 x TPB=1024 — same per-thread
// register economy (a[16][8] at the 256-arch-VGPR boundary), half the
// exchange degree: 2 parties, 256 foreign words, 1 peer's skew.
//   word idx: row i of slot par lives at g_tags[(par*512 + i)*8] (line-spread)
//   hello words at g_tags[8192 + s*16]
__device__ unsigned long long g_tags[8192 + 64];
#define G_HELLO 8192

__device__ __forceinline__ long long rt() {
    return (long long)__builtin_amdgcn_s_memrealtime();
}

// publish + wait (handshake only)
__device__ __forceinline__ void st_pub(unsigned long long* p, unsigned long long v) {
    asm volatile("global_atomic_swap_x2 %0, %1, off\n\ts_waitcnt vmcnt(0)"
                 :: "v"(p), "v"(v) : "memory");
}

// publish fire-and-forget (data plane): swap is atomic 8B, self-ordering
__device__ __forceinline__ void st_pub_nw(unsigned long long* p, unsigned long long v) {
    asm volatile("global_atomic_swap_x2 %0, %1, off"
                 :: "v"(p), "v"(v) : "memory");
}

// read via atomic add-0 (sc0 = return old) -> L2-served (R5-proven)
__device__ __forceinline__ unsigned long long ld_atom(const unsigned long long* p) {
    unsigned long long v;
    const unsigned long long z = 0;
    asm volatile("global_atomic_add_x2 %0, %1, %2, off sc0\n\ts_waitcnt vmcnt(0)"
                 : "=&v"(v) : "v"(p), "v"(z) : "memory");
    return v;
}

__global__ __launch_bounds__(TPB, 4)
void flow_main(const float* __restrict__ x0,
               const float* __restrict__ tt,
               const float* __restrict__ uc,   // (4, 4095, 32): d,c,b,a
               const float* __restrict__ A,    // (512, 512)
               const float* __restrict__ B,    // (512, 32)
               float* __restrict__ xs,         // (4096, 512)
               unsigned long long* __restrict__ XX)
{
    const int tid = threadIdx.x;
    __shared__ int s_sb, s_mode;     // 0=heater, 1=FAST(L2 atomics), 2=SLOW(agent)
    __shared__ unsigned s_n32;       // per-run tag nonce (FAST)
    __shared__ float xb[2][NS];      // LDS exchange buffers (FAST mode)
    __shared__ int wflag[16];        // per-wave stage flags (release/acquire)

    if (tid == 0) {
        s_n32 = 0;
#pragma unroll
        for (int i = 0; i < 16; ++i) wflag[i] = -1;
        unsigned xcc;
        asm volatile("s_getreg_b32 %0, hwreg(HW_REG_XCC_ID)" : "=s"(xcc));
        xcc &= 7u;

        const unsigned long long old = __hip_atomic_fetch_add(
            &XX[W_CNT + (int)xcc * 16], 1ull,
            __ATOMIC_RELAXED, __HIP_MEMORY_SCOPE_AGENT);
        const int slot = (int)(unsigned)(old - POISON64);
        if (slot == GK - 1) {
            unsigned long long exp = POISON64;
            __hip_atomic_compare_exchange_strong(
                &XX[W_WIN], &exp, (unsigned long long)xcc,
                __ATOMIC_RELAXED, __ATOMIC_RELAXED, __HIP_MEMORY_SCOPE_AGENT);
        }
        long long t0 = rt();
        unsigned long long wv;
        for (;;) {
            wv = __hip_atomic_load(&XX[W_WIN], __ATOMIC_RELAXED,
                                   __HIP_MEMORY_SCOPE_AGENT);
            if (wv != POISON64) break;
            if (rt() - t0 > CAP_ELECT) break;
        }

        int mode = 0, sb = slot;
        if (wv == POISON64) {
            sb = blockIdx.x;                       // unreachable failsafe
            mode = (blockIdx.x < GK) ? 2 : 0;
        } else if ((unsigned long long)xcc == wv && slot < GK) {
            // -- distribute per-run nonce over the PROVEN d_ws control plane --
            unsigned long long nonce = POISON64;
            if (slot == 0) {
                nonce = ((unsigned long long)rt() << 1) | 1ull;  // odd != POISON64
                __hip_atomic_store(&XX[W_NONCE], nonce,
                                   __ATOMIC_RELAXED, __HIP_MEMORY_SCOPE_AGENT);
            } else {
                long long tn = rt();
                for (;;) {
                    nonce = __hip_atomic_load(&XX[W_NONCE], __ATOMIC_RELAXED,
                                              __HIP_MEMORY_SCOPE_AGENT);
                    if (nonce != POISON64) break;
                    if (rt() - tn > CAP_HAND) break;
                }
            }
            if (nonce == POISON64) {
                mode = 2;   // control-plane hiccup: proven SLOW path
            } else {
                // -- two-phase handshake over the exact FAST primitive pair --
                const unsigned long long H1 = H1V ^ nonce, H2 = H2V ^ nonce;
                unsigned long long* hme = &g_tags[G_HELLO + slot * 16];
                st_pub(hme, H1);
                if (slot == 0) {
                    bool ok = true;
                    long long th = rt();
                    for (int i = 1; i < GK && ok; ++i)
                        for (;;) {
                            const unsigned long long h = ld_atom(&g_tags[G_HELLO + i * 16]);
                            if (h == H1 || h == H2) break;
                            if (rt() - th > CAP_HAND) { ok = false; break; }
                        }
                    st_pub(hme, H2);
                    th = rt();
                    for (int i = 1; i < GK && ok; ++i)
                        for (;;) {
                            const unsigned long long h = ld_atom(&g_tags[G_HELLO + i * 16]);
                            if (h == H2) break;
                            if (rt() - th > CAP_HAND) { ok = false; break; }
                        }
                    __hip_atomic_store(&XX[W_DEC], ok ? 1ull : 2ull,
                                       __ATOMIC_RELAXED, __HIP_MEMORY_SCOPE_AGENT);
                    mode = ok ? 1 : 2;
                } else {
                    long long th = rt();
                    for (;;) {
                        const unsigned long long h = ld_atom(&g_tags[G_HELLO + 0]);
                        if (h == H2) break;
                        if (rt() - th > CAP_HAND) break;
                    }
                    st_pub(hme, H2);
                    th = rt();
                    unsigned long long dv;
                    for (;;) {
                        dv = __hip_atomic_load(&XX[W_DEC], __ATOMIC_RELAXED,
                                               __HIP_MEMORY_SCOPE_AGENT);
                        if (dv != POISON64) break;
                        if (rt() - th > CAP_DEC) { dv = 2ull; break; }
                    }
                    mode = (dv == 1ull) ? 1 : 2;
                }
                s_n32 = (unsigned)nonce;
            }
        }
        s_sb = sb; s_mode = mode;
    }
    __syncthreads();
    const int mode = s_mode;
    const int sb   = s_sb;
    const unsigned n32 = s_n32;

    if (mode == 0) {
        // HEATER blocks (R2: proven clock not parked; kept as controlled var)
        float h0 = (float)tid * 1e-6f + 0.05f;
        float h1 = h0 + 0.17f, h2 = h0 + 0.39f, h3 = h0 + 0.71f;
        const long long t0 = rt();
        for (;;) {
            for (int ot = 0; ot < 64; ++ot) {
#pragma unroll
                for (int it = 0; it < 128; ++it) {
                    h0 = fmaf(h0, 0.9999999f, 1e-7f);
                    h1 = fmaf(h1, 0.9999998f, 2e-7f);
                    h2 = fmaf(h2, 0.9999997f, 3e-7f);
                    h3 = fmaf(h3, 0.9999996f, 4e-7f);
                }
            }
            if (__hip_atomic_load(&XX[W_DONE], __ATOMIC_RELAXED,
                                  __HIP_MEMORY_SCOPE_AGENT) == DONEV) break;
            if (rt() - t0 > CAP_HEAT) break;
        }
        if (h0 + h1 + h2 + h3 == 123.4567f)   // never true; keeps hz alive
            ((float*)XX)[8 * W_SINK] = h0;
        return;
    }
    const bool fast = (mode == 1);

    // ---- integrator: 16 waves x 16 rows = 256 rows/CU, 2 CUs ----
    const int l = tid & 63;
    const int w = tid >> 6;                         // wave 0..15
    const int rloc = ((l >> 5) & 1) | (((l >> 4) & 1) << 1)
                   | (((l >> 3) & 1) << 2) | (((l >> 2) & 1) << 3);
    const int rbase = sb * 256 + w * 16;
    const int r     = rbase + rloc;                 // my quad's row
    const int ch0   = (l & 3) * 8;                  // my 8 B/uc channels
    const int psb   = 1 - sb;                       // peer block

    const float dt = tt[1] - tt[0];

    float a[16][8];                                 // A[rbase+i][j*64+l]
#pragma unroll
    for (int i = 0; i < 16; ++i)
#pragma unroll
        for (int j = 0; j < 8; ++j)
            a[i][j] = A[(rbase + i) * NS + j * 64 + l];

    float B8[8];
    {
        const float4 b0 = *(const float4*)&B[r * NI + ch0];
        const float4 b1 = *(const float4*)&B[r * NI + ch0 + 4];
        B8[0] = b0.x; B8[1] = b0.y; B8[2] = b0.z; B8[3] = b0.w;
        B8[4] = b1.x; B8[5] = b1.y; B8[6] = b1.z; B8[7] = b1.w;
    }

    float x = x0[r];
    float xv[8];
#pragma unroll
    for (int j = 0; j < 8; ++j) xv[j] = x0[j * 64 + l];
    if ((l & 3) == 0) xs[r] = x;

    // heater state (kept live via sink)
    float hz0 = (float)(tid) * 1e-6f + 0.1f;
    float hz1 = hz0 + 0.3f, hz2 = hz0 + 0.7f, hz3 = hz0 + 1.1f;

    const float SOFF[6] = {0.0f, 0.2f * dt, 0.3f * dt, 0.8f * dt,
                           (8.0f / 9.0f) * dt, dt};
    float k[6];
    const long long tstart = rt();

    for (int n = 0; n < NSTEP; ++n) {
        const float* un = uc + n * NI + ch0;
        float pq[4];
#pragma unroll
        for (int qq = 0; qq < 4; ++qq) {
            const float4 v0 = *(const float4*)(un + qq * (NSTEP * NI));
            const float4 v1 = *(const float4*)(un + qq * (NSTEP * NI) + 4);
            float s0 = B8[0]*v0.x + B8[1]*v0.y + B8[2]*v0.z + B8[3]*v0.w
                     + B8[4]*v1.x + B8[5]*v1.y + B8[6]*v1.z + B8[7]*v1.w;
            s0 += __shfl_xor(s0, 1, 64);
            s0 += __shfl_xor(s0, 2, 64);
            pq[qq] = s0;
        }
        const float pd = pq[0], pc = pq[1], pb = pq[2], pa = pq[3];

#pragma unroll
        for (int s = 0; s < 6; ++s) {
            const int gs = n * 6 + s;

            if (gs != 0) {
                if (fast) {
                    const unsigned par = (unsigned)gs & 1u;
                    const unsigned g = (unsigned)gs + n32;
                    if (w == 0) {
                        // FAST beacon: 32-way LDS conflict read; counter
                        // SQ_LDS_BANK_CONFLICT >= ~1M proves FAST engaged
                        unsigned bdum;
                        const unsigned baddr = ((l & 31) << 7) | ((l >> 5) << 2);
                        asm volatile("ds_read_b32 %0, %1\n\ts_waitcnt lgkmcnt(0)"
                                     : "=v"(bdum) : "v"(baddr));
                    }
                    // sliced detection: wave w's lanes 0..15 poll peer rows
                    // psb*256 + w*16 + l, ONE RMW/lane/sweep, line-spread
                    const int pr = psb * 256 + w * 16 + (l & 15);
                    const unsigned long long* p =
                        g_tags + (par * 512u + (unsigned)pr) * 8u;
                    bool done = (l >= 16);
                    unsigned long long v = 0;
                    unsigned sweep = 0;
                    for (;;) {
                        if (!done) {
                            v = ld_atom(p);
                            if ((unsigned)(v >> 32) == g) done = true;
                        }
                        if (__all(done)) break;
                        if (((++sweep) & 0x3FFu) == 0 &&
                            rt() - tstart > CAP_POLL)
                            return;
                    }
                    if (l < 16) xb[par][pr] = __uint_as_float((unsigned)v);
                    // own 256 rows arrived via writers' LDS stores at the
                    // end of stage gs-1 (before each wave's flag release)
                    if (l == 0)
                        __hip_atomic_store(&wflag[w], gs, __ATOMIC_RELEASE,
                                           __HIP_MEMORY_SCOPE_WORKGROUP);
                    // wait for all 16 waves (lane i checks flag i&15)
                    unsigned fsw = 0;
                    for (;;) {
                        const int m = __hip_atomic_load(
                            &wflag[l & 15], __ATOMIC_ACQUIRE,
                            __HIP_MEMORY_SCOPE_WORKGROUP);
                        if (__all(m >= gs)) break;
                        if (((++fsw) & 0x3FFFu) == 0 &&
                            rt() - tstart > CAP_POLL)
                            return;
                    }
#pragma unroll
                    for (int j = 0; j < 8; ++j)
                        xv[j] = xb[par][j * 64 + l];
                } else {
                    // SLOW: proven agent-scope poll over d_ws (per-thread)
                    unsigned long long* p =
                        (unsigned long long*)XX + ((unsigned)gs & 1u) * NS + l;
                    unsigned done = 0, sweep = 0;
                    unsigned long long v[8];
                    while (done != 0xFFu) {
#pragma unroll
                        for (int j = 0; j < 8; ++j)
                            if (!(done & (1u << j)))
                                v[j] = __hip_atomic_load(
                                    p + 64 * j, __ATOMIC_RELAXED,
                                    __HIP_MEMORY_SCOPE_AGENT);
#pragma unroll
                        for (int j = 0; j < 8; ++j) {
                            if (!(done & (1u << j))) {
                                if (__all((unsigned)(v[j] >> 32) == (unsigned)gs)) {
                                    xv[j] = __uint_as_float((unsigned)v[j]);
                                    done |= (1u << j);
                                }
                            }
                        }
                        if (((++sweep) & 0xFFFu) == 0 &&
                            rt() - tstart > CAP_POLL)
                            return;
                    }
                }
            }

            float sc[16];
#pragma unroll
            for (int i = 0; i < 16; ++i) sc[i] = 0.0f;
#pragma unroll
            for (int j = 0; j < 8; ++j)
#pragma unroll
                for (int i = 0; i < 16; ++i)
                    sc[i] = fmaf(a[i][j], xv[j], sc[i]);

            // pack-butterfly: 16 row sums over 64 lanes
            float t8[8];
#pragma unroll
            for (int i = 0; i < 8; ++i) {
                const float send = (l & 32) ? sc[2*i] : sc[2*i+1];
                const float keep = (l & 32) ? sc[2*i+1] : sc[2*i];
                t8[i] = keep + __shfl_xor(send, 32, 64);
            }
            float t4[4];
#pragma unroll
            for (int i = 0; i < 4; ++i) {
                const float send = (l & 16) ? t8[2*i] : t8[2*i+1];
                const float keep = (l & 16) ? t8[2*i+1] : t8[2*i];
                t4[i] = keep + __shfl_xor(send, 16, 64);
            }
            float t2[2];
#pragma unroll
            for (int i = 0; i < 2; ++i) {
                const float send = (l & 8) ? t4[2*i] : t4[2*i+1];
                const float keep = (l & 8) ? t4[2*i+1] : t4[2*i];
                t2[i] = keep + __shfl_xor(send, 8, 64);
            }
            float t1;
            {
                const float send = (l & 4) ? t2[0] : t2[1];
                const float keep = (l & 4) ? t2[1] : t2[0];
                t1 = keep + __shfl_xor(send, 4, 64);
                t1 += __shfl_xor(t1, 2, 64);
                t1 += __shfl_xor(t1, 1, 64);
            }

            const float sv = SOFF[s];
            const float bu = pa + sv * (pb + sv * (pc + sv * pd));
            const float e  = __expf(2.0f * t1);
            k[s] = (1.0f - 2.0f / (e + 1.0f)) + bu;

            float nxt;
            if (s == 0) {
                nxt = x + dt * (0.2f * k[0]);
            } else if (s == 1) {
                nxt = x + dt * ((3.0f / 40.0f) * k[0] + (9.0f / 40.0f) * k[1]);
            } else if (s == 2) {
                nxt = x + dt * ((44.0f / 45.0f) * k[0] + (-56.0f / 15.0f) * k[1] +
                                (32.0f / 9.0f) * k[2]);
            } else if (s == 3) {
                nxt = x + dt * ((19372.0f / 6561.0f) * k[0] + (-25360.0f / 2187.0f) * k[1] +
                                (64448.0f / 6561.0f) * k[2] + (-212.0f / 729.0f) * k[3]);
            } else if (s == 4) {
                nxt = x + dt * ((9017.0f / 3168.0f) * k[0] + (-355.0f / 33.0f) * k[1] +
                                (46732.0f / 5247.0f) * k[2] + (49.0f / 176.0f) * k[3] +
                                (-5103.0f / 18656.0f) * k[4]);
            } else {
                nxt = x + dt * ((35.0f / 384.0f) * k[0] + (500.0f / 1113.0f) * k[2] +
                                (125.0f / 192.0f) * k[3] + (-2187.0f / 6784.0f) * k[4] +
                                (11.0f / 84.0f) * k[5]);
                x = nxt;
                if ((l & 3) == 0) xs[(n + 1) * NS + r] = nxt;
            }

            if ((l & 3) == 0) {
                const unsigned sidx = (unsigned)(gs + 1) & 1u;   // slot parity by stage
                if (fast) {
                    // own value into LDS (local 256 bypass global) +
                    // line-spread fire-and-forget publish for the peer
                    xb[sidx][r] = nxt;
                    const unsigned long long pv =
                        ((unsigned long long)((unsigned)(gs + 1) + n32) << 32) |
                        (unsigned long long)__float_as_uint(nxt);
                    st_pub_nw(g_tags + (sidx * 512u + (unsigned)r) * 8u, pv);
                } else {
                    const unsigned long long pv =
                        ((unsigned long long)(unsigned)(gs + 1) << 32) |
                        (unsigned long long)__float_as_uint(nxt);
                    __hip_atomic_store(XX + sidx * NS + r, pv, __ATOMIC_RELAXED,
                                       __HIP_MEMORY_SCOPE_AGENT);
                }
            }
        }
    }

    // workers done: release the heater blocks (idempotent, both CUs write)
    if (tid == 0)
        __hip_atomic_store(&XX[W_DONE], DONEV, __ATOMIC_RELAXED,
                           __HIP_MEMORY_SCOPE_AGENT);

    // keep hz alive (never true at runtime; compiler can't prove it)
    if (hz0 + hz1 + hz2 + hz3 == 123.4567f)
        ((float*)XX)[8 * W_SINK] = hz0;
}

__global__ __launch_bounds__(256, 1)
void flow_ys(const float* __restrict__ xs,  // (4096, 512)
             const float* __restrict__ C,   // (16, 512)
             float* __restrict__ ys)        // (4096, 16)
{
    const int step = blockIdx.x;
    const int lane = threadIdx.x & 63;
    const int wv   = threadIdx.x >> 6;  // 0..3
    const float* xrow = xs + step * NS;

#pragma unroll
    for (int oo = 0; oo < 4; ++oo) {
        const int o = (wv << 2) + oo;
        float p = 0.0f;
#pragma unroll
        for (int j = 0; j < 8; ++j)
            p += C[o * NS + lane + 64 * j] * xrow[lane + 64 * j];
#pragma unroll
        for (int m = 1; m < 64; m <<= 1) p += __shfl_xor(p, m, 64);
        if (lane == 0) ys[step * NO + o] = p;
    }
}

extern "C" void kernel_launch(void* const* d_in, const int* in_sizes, int n_in,
                              void* d_out, int out_size, void* d_ws, size_t ws_size,
                              hipStream_t stream) {
    const float* x0 = (const float*)d_in[0];
    const float* t  = (const float*)d_in[1];
    const float* uc = (const float*)d_in[2];
    const float* A  = (const float*)d_in[3];
    const float* B  = (const float*)d_in[4];
    const float* C  = (const float*)d_in[5];

    float* xs = (float*)d_out;            // 4096*512
    float* ys = xs + TT * NS;             // 4096*16
    unsigned long long* XX = (unsigned long long*)d_ws;  // < 11 KB used

    flow_main<<<NBLK_TOT, TPB, 0, stream>>>(x0, t, uc, A, B, xs, XX);
    flow_ys<<<TT, 256, 0, stream>>>(xs, C, ys);
}

// Round 12
// 105961.682 us; speedup vs baseline: 2.9727x; 2.9727x over previous
//
#include <hip/hip_runtime.h>
#include <math.h>

#define NS 512          // states
#define NI 32           // inputs
#define NO 16           // outputs
#define TT 4096         // time points
#define NSTEP (TT - 1)  // 4095 integration steps
#define TPB 512
#define NBLK_TOT 64     // launched blocks; 4 co-XCD blocks win the election
#define GK 4            // group size. R11 PROVED GK=4 is the register-topology
                        // optimum: A-block 128rows=256KB/CU = half the 512KB RF.
                        // GK=2 needs the whole RF -> VGPR cap 64 -> scratch
                        // spills -> 315ms. Do not revisit the CU-count axis.

// ---- control plane: d_ws (re-poisoned each iteration; agent-scope proven) ----
#define W_CNT   1024
#define W_WIN   1200
#define W_DEC   1280
#define W_SINK  1320
#define W_DONE  1336
#define W_NONCE 1352
#define POISON64 0xAAAAAAAAAAAAAAAAull
#define H1V 0x1111000011110001ull
#define H2V 0x2222000022220002ull
#define DONEV 0x600D600D600D600Dull
#define CAP_ELECT  10000000ll    // 0.1 s @ 100 MHz s_memrealtime
#define CAP_HAND    1000000ll    // 10 ms
#define CAP_DEC    50000000ll    // 0.5 s
#define CAP_POLL   30000000ll    // 0.3 s failsafe
#define CAP_HEAT   30000000ll    // 0.3 s failsafe for heater blocks

// ---- data plane: module-scope device global (coarse VRAM). ----
// Primitive matrix (R0-R10): plain load = stale L1; sc0/nt load = MALL;
// atomic add0 = the only L2-served read; publish = unscoped atomic swap
// (TCC-executed, L2-resident, fire-and-forget safe). R10 = 48.1ms (GK=4,
// line-spread tags, own-block LDS bypass, sliced detection).
// R12: OVERLAPPED CONSUMPTION — dual flags (wofl: own xb rows visible,
// released BEFORE polling; wffl: foreign slice in xb). Each wave FMAs
// column-blocks as they become ready, so the ~450cy of FMA issue hides
// under the detect RTT instead of serializing after it. All a[i][j]
// indices compile-time constant (R11 scratch-spill lesson).
//   word idx: row i of slot par lives at g_tags[(par*512 + i)*8] (line-spread)
//   hello words at g_tags[8192 + s*16]
__device__ unsigned long long g_tags[8192 + 64];
#define G_HELLO 8192

__device__ __forceinline__ long long rt() {
    return (long long)__builtin_amdgcn_s_memrealtime();
}

// publish + wait (handshake only)
__device__ __forceinline__ void st_pub(unsigned long long* p, unsigned long long v) {
    asm volatile("global_atomic_swap_x2 %0, %1, off\n\ts_waitcnt vmcnt(0)"
                 :: "v"(p), "v"(v) : "memory");
}

// publish fire-and-forget (data plane): swap is atomic 8B, self-ordering
__device__ __forceinline__ void st_pub_nw(unsigned long long* p, unsigned long long v) {
    asm volatile("global_atomic_swap_x2 %0, %1, off"
                 :: "v"(p), "v"(v) : "memory");
}

// read via atomic add-0 (sc0 = return old) -> L2-served (R5-proven)
__device__ __forceinline__ unsigned long long ld_atom(const unsigned long long* p) {
    unsigned long long v;
    const unsigned long long z = 0;
    asm volatile("global_atomic_add_x2 %0, %1, %2, off sc0\n\ts_waitcnt vmcnt(0)"
                 : "=&v"(v) : "v"(p), "v"(z) : "memory");
    return v;
}

// TRYJ(J): if column-block J not yet accumulated and ready, FMA it.
// J is a compile-time constant in every expansion -> a[i][J] stays in regs.
#define TRYJ(J)                                                              \
    if (!(jmask & (1u << (J)))) {                                            \
        bool rdy;                                                            \
        if (((J) >> 1) == sb) {                                              \
            const int fb = ((J) & 1) * 4;                                    \
            rdy = (__hip_atomic_load(&wofl[fb+0], __ATOMIC_ACQUIRE,          \
                       __HIP_MEMORY_SCOPE_WORKGROUP) >= gs)                  \
               && (__hip_atomic_load(&wofl[fb+1], __ATOMIC_ACQUIRE,          \
                       __HIP_MEMORY_SCOPE_WORKGROUP) >= gs)                  \
               && (__hip_atomic_load(&wofl[fb+2], __ATOMIC_ACQUIRE,          \
                       __HIP_MEMORY_SCOPE_WORKGROUP) >= gs)                  \
               && (__hip_atomic_load(&wofl[fb+3], __ATOMIC_ACQUIRE,          \
                       __HIP_MEMORY_SCOPE_WORKGROUP) >= gs);                 \
        } else {                                                             \
            rdy = (__hip_atomic_load(&wffl[(J)], __ATOMIC_ACQUIRE,           \
                       __HIP_MEMORY_SCOPE_WORKGROUP) >= gs);                 \
        }                                                                    \
        if (rdy) {                                                           \
            const float xvj = xb[par][(J) * 64 + l];                         \
            _Pragma("unroll")                                                \
            for (int i = 0; i < 16; ++i)                                     \
                sc[i] = fmaf(a[i][(J)], xvj, sc[i]);                         \
            jmask |= (1u << (J));                                            \
        }                                                                    \
    }

#define TRY_ALL TRYJ(0) TRYJ(1) TRYJ(2) TRYJ(3) TRYJ(4) TRYJ(5) TRYJ(6) TRYJ(7)

__global__ __launch_bounds__(TPB, 2)
void flow_main(const float* __restrict__ x0,
               const float* __restrict__ tt,
               const float* __restrict__ uc,   // (4, 4095, 32): d,c,b,a
               const float* __restrict__ A,    // (512, 512)
               const float* __restrict__ B,    // (512, 32)
               float* __restrict__ xs,         // (4096, 512)
               unsigned long long* __restrict__ XX)
{
    const int tid = threadIdx.x;
    __shared__ int s_sb, s_mode;     // 0=heater, 1=FAST(L2 atomics), 2=SLOW(agent)
    __shared__ unsigned s_n32;       // per-run tag nonce (FAST)
    __shared__ float xb[2][NS];      // LDS exchange buffers (FAST mode)
    __shared__ int wofl[8];          // per-wave "own xb rows written" flags
    __shared__ int wffl[8];          // per-wave "foreign slice written" flags

    if (tid == 0) {
        s_n32 = 0;
#pragma unroll
        for (int i = 0; i < 8; ++i) { wofl[i] = 0; wffl[i] = 0; }
        unsigned xcc;
        asm volatile("s_getreg_b32 %0, hwreg(HW_REG_XCC_ID)" : "=s"(xcc));
        xcc &= 7u;

        const unsigned long long old = __hip_atomic_fetch_add(
            &XX[W_CNT + (int)xcc * 16], 1ull,
            __ATOMIC_RELAXED, __HIP_MEMORY_SCOPE_AGENT);
        const int slot = (int)(unsigned)(old - POISON64);
        if (slot == GK - 1) {
            unsigned long long exp = POISON64;
            __hip_atomic_compare_exchange_strong(
                &XX[W_WIN], &exp, (unsigned long long)xcc,
                __ATOMIC_RELAXED, __ATOMIC_RELAXED, __HIP_MEMORY_SCOPE_AGENT);
        }
        long long t0 = rt();
        unsigned long long wv;
        for (;;) {
            wv = __hip_atomic_load(&XX[W_WIN], __ATOMIC_RELAXED,
                                   __HIP_MEMORY_SCOPE_AGENT);
            if (wv != POISON64) break;
            if (rt() - t0 > CAP_ELECT) break;
        }

        int mode = 0, sb = slot;
        if (wv == POISON64) {
            sb = blockIdx.x;                       // unreachable failsafe
            mode = (blockIdx.x < GK) ? 2 : 0;
        } else if ((unsigned long long)xcc == wv && slot < GK) {
            // -- distribute per-run nonce over the PROVEN d_ws control plane --
            unsigned long long nonce = POISON64;
            if (slot == 0) {
                nonce = ((unsigned long long)rt() << 1) | 1ull;  // odd != POISON64
                __hip_atomic_store(&XX[W_NONCE], nonce,
                                   __ATOMIC_RELAXED, __HIP_MEMORY_SCOPE_AGENT);
            } else {
                long long tn = rt();
                for (;;) {
                    nonce = __hip_atomic_load(&XX[W_NONCE], __ATOMIC_RELAXED,
                                              __HIP_MEMORY_SCOPE_AGENT);
                    if (nonce != POISON64) break;
                    if (rt() - tn > CAP_HAND) break;
                }
            }
            if (nonce == POISON64) {
                mode = 2;   // control-plane hiccup: proven SLOW path
            } else {
                // -- two-phase handshake over the exact FAST primitive pair --
                const unsigned long long H1 = H1V ^ nonce, H2 = H2V ^ nonce;
                unsigned long long* hme = &g_tags[G_HELLO + slot * 16];
                st_pub(hme, H1);
                if (slot == 0) {
                    bool ok = true;
                    long long th = rt();
                    for (int i = 1; i < GK && ok; ++i)
                        for (;;) {
                            const unsigned long long h = ld_atom(&g_tags[G_HELLO + i * 16]);
                            if (h == H1 || h == H2) break;
                            if (rt() - th > CAP_HAND) { ok = false; break; }
                        }
                    st_pub(hme, H2);
                    th = rt();
                    for (int i = 1; i < GK && ok; ++i)
                        for (;;) {
                            const unsigned long long h = ld_atom(&g_tags[G_HELLO + i * 16]);
                            if (h == H2) break;
                            if (rt() - th > CAP_HAND) { ok = false; break; }
                        }
                    __hip_atomic_store(&XX[W_DEC], ok ? 1ull : 2ull,
                                       __ATOMIC_RELAXED, __HIP_MEMORY_SCOPE_AGENT);
                    mode = ok ? 1 : 2;
                } else {
                    long long th = rt();
                    for (;;) {
                        const unsigned long long h = ld_atom(&g_tags[G_HELLO + 0]);
                        if (h == H2) break;
                        if (rt() - th > CAP_HAND) break;
                    }
                    st_pub(hme, H2);
                    th = rt();
                    unsigned long long dv;
                    for (;;) {
                        dv = __hip_atomic_load(&XX[W_DEC], __ATOMIC_RELAXED,
                                               __HIP_MEMORY_SCOPE_AGENT);
                        if (dv != POISON64) break;
                        if (rt() - th > CAP_DEC) { dv = 2ull; break; }
                    }
                    mode = (dv == 1ull) ? 1 : 2;
                }
                s_n32 = (unsigned)nonce;
            }
        }
        s_sb = sb; s_mode = mode;
    }
    __syncthreads();
    const int mode = s_mode;
    const int sb   = s_sb;
    const unsigned n32 = s_n32;

    if (mode == 0) {
        // HEATER blocks (R2: proven clock not parked; kept as controlled var)
        float h0 = (float)tid * 1e-6f + 0.05f;
        float h1 = h0 + 0.17f, h2 = h0 + 0.39f, h3 = h0 + 0.71f;
        const long long t0 = rt();
        for (;;) {
            for (int ot = 0; ot < 64; ++ot) {
#pragma unroll
                for (int it = 0; it < 128; ++it) {
                    h0 = fmaf(h0, 0.9999999f, 1e-7f);
                    h1 = fmaf(h1, 0.9999998f, 2e-7f);
                    h2 = fmaf(h2, 0.9999997f, 3e-7f);
                    h3 = fmaf(h3, 0.9999996f, 4e-7f);
                }
            }
            if (__hip_atomic_load(&XX[W_DONE], __ATOMIC_RELAXED,
                                  __HIP_MEMORY_SCOPE_AGENT) == DONEV) break;
            if (rt() - t0 > CAP_HEAT) break;
        }
        if (h0 + h1 + h2 + h3 == 123.4567f)   // never true; keeps hz alive
            ((float*)XX)[8 * W_SINK] = h0;
        return;
    }
    const bool fast = (mode == 1);

    // ---- integrator (R10 layout + R12 overlapped consumption) ----
    const int l = tid & 63;
    const int w = tid >> 6;                         // wave 0..7
    const int rloc = ((l >> 5) & 1) | (((l >> 4) & 1) << 1)
                   | (((l >> 3) & 1) << 2) | (((l >> 2) & 1) << 3);
    const int rbase = sb * 128 + w * 16;
    const int r     = rbase + rloc;                 // my quad's row
    const int ch0   = (l & 3) * 8;                  // my 8 B/uc channels
    const int sl    = w * 64 + l;                   // my detection-slice word
    const bool slice_foreign = ((w >> 1) != sb);    // whole-wave uniform

    const float dt = tt[1] - tt[0];

    float a[16][8];                                 // A[rbase+i][j*64+l]
#pragma unroll
    for (int i = 0; i < 16; ++i)
#pragma unroll
        for (int j = 0; j < 8; ++j)
            a[i][j] = A[(rbase + i) * NS + j * 64 + l];

    float B8[8];
    {
        const float4 b0 = *(const float4*)&B[r * NI + ch0];
        const float4 b1 = *(const float4*)&B[r * NI + ch0 + 4];
        B8[0] = b0.x; B8[1] = b0.y; B8[2] = b0.z; B8[3] = b0.w;
        B8[4] = b1.x; B8[5] = b1.y; B8[6] = b1.z; B8[7] = b1.w;
    }

    float x = x0[r];
    float xv[8];                                    // used at gs==0 and SLOW
#pragma unroll
    for (int j = 0; j < 8; ++j) xv[j] = x0[j * 64 + l];
    if ((l & 3) == 0) xs[r] = x;

    // heater state (kept live via sink)
    float hz0 = (float)(tid) * 1e-6f + 0.1f;
    float hz1 = hz0 + 0.3f, hz2 = hz0 + 0.7f, hz3 = hz0 + 1.1f;

    const float SOFF[6] = {0.0f, 0.2f * dt, 0.3f * dt, 0.8f * dt,
                           (8.0f / 9.0f) * dt, dt};
    float k[6];
    const long long tstart = rt();

    for (int n = 0; n < NSTEP; ++n) {
        const float* un = uc + n * NI + ch0;
        float pq[4];
#pragma unroll
        for (int qq = 0; qq < 4; ++qq) {
            const float4 v0 = *(const float4*)(un + qq * (NSTEP * NI));
            const float4 v1 = *(const float4*)(un + qq * (NSTEP * NI) + 4);
            float s0 = B8[0]*v0.x + B8[1]*v0.y + B8[2]*v0.z + B8[3]*v0.w
                     + B8[4]*v1.x + B8[5]*v1.y + B8[6]*v1.z + B8[7]*v1.w;
            s0 += __shfl_xor(s0, 1, 64);
            s0 += __shfl_xor(s0, 2, 64);
            pq[qq] = s0;
        }
        const float pd = pq[0], pc = pq[1], pb = pq[2], pa = pq[3];

#pragma unroll
        for (int s = 0; s < 6; ++s) {
            const int gs = n * 6 + s;

            float sc[16];
#pragma unroll
            for (int i = 0; i < 16; ++i) sc[i] = 0.0f;

            if (gs != 0 && fast) {
                const unsigned par = (unsigned)gs & 1u;
                const unsigned g = (unsigned)gs + n32;
                // my 16 xb rows (slot par) were written at end of gs-1:
                // release BEFORE polling so own blocks unblock locally
                __hip_atomic_store(&wofl[w], gs, __ATOMIC_RELEASE,
                                   __HIP_MEMORY_SCOPE_WORKGROUP);
                unsigned jmask = 0;
                if (w == 0) {
                    // FAST beacon: 32-way LDS conflict read (mode telemetry)
                    unsigned bdum;
                    const unsigned baddr = ((l & 31) << 7) | ((l >> 5) << 2);
                    asm volatile("ds_read_b32 %0, %1\n\ts_waitcnt lgkmcnt(0)"
                                 : "=v"(bdum) : "v"(baddr));
                }
                if (slice_foreign) {
                    // async poll: issue, FMA ready blocks, then wait+check.
                    // "+v"(pv) pins the data dependency so the tag check
                    // cannot hoist above the waitcnt (rule #18 analog).
                    const unsigned long long* p =
                        g_tags + (par * 512u + (unsigned)sl) * 8u;
                    const unsigned long long z = 0;
                    unsigned long long pv;
                    asm volatile("global_atomic_add_x2 %0, %1, %2, off sc0"
                                 : "=&v"(pv) : "v"(p), "v"(z) : "memory");
                    unsigned sweep = 0;
                    for (;;) {
                        TRY_ALL
                        asm volatile("s_waitcnt vmcnt(0)"
                                     : "+v"(pv) :: "memory");
                        if ((unsigned)(pv >> 32) == g) break;
                        asm volatile("global_atomic_add_x2 %0, %1, %2, off sc0"
                                     : "=&v"(pv) : "v"(p), "v"(z) : "memory");
                        if (((++sweep) & 0xFFu) == 0 &&
                            rt() - tstart > CAP_POLL)
                            return;
                    }
                    xb[par][sl] = __uint_as_float((unsigned)pv);
                    __hip_atomic_store(&wffl[w], gs, __ATOMIC_RELEASE,
                                       __HIP_MEMORY_SCOPE_WORKGROUP);
                } else {
                    __hip_atomic_store(&wffl[w], gs, __ATOMIC_RELEASE,
                                       __HIP_MEMORY_SCOPE_WORKGROUP);
                }
                // drain remaining blocks as they land
                unsigned fsw = 0;
                while (jmask != 0xFFu) {
                    TRY_ALL
                    if (((++fsw) & 0x3FFu) == 0 &&
                        rt() - tstart > CAP_POLL)
                        return;
                }
            } else {
                if (gs != 0) {
                    // SLOW: proven agent-scope poll over d_ws (all waves)
                    unsigned long long* p =
                        (unsigned long long*)XX + ((unsigned)gs & 1u) * NS + l;
                    unsigned done = 0, sweep = 0;
                    unsigned long long v[8];
                    while (done != 0xFFu) {
#pragma unroll
                        for (int j = 0; j < 8; ++j)
                            if (!(done & (1u << j)))
                                v[j] = __hip_atomic_load(
                                    p + 64 * j, __ATOMIC_RELAXED,
                                    __HIP_MEMORY_SCOPE_AGENT);
#pragma unroll
                        for (int j = 0; j < 8; ++j) {
                            if (!(done & (1u << j))) {
                                if (__all((unsigned)(v[j] >> 32) == (unsigned)gs)) {
                                    xv[j] = __uint_as_float((unsigned)v[j]);
                                    done |= (1u << j);
                                }
                            }
                        }
                        if (((++sweep) & 0xFFFu) == 0 &&
                            rt() - tstart > CAP_POLL)
                            return;
                    }
                }
#pragma unroll
                for (int j = 0; j < 8; ++j)
#pragma unroll
                    for (int i = 0; i < 16; ++i)
                        sc[i] = fmaf(a[i][j], xv[j], sc[i]);
            }

            // pack-butterfly: 16 row sums over 64 lanes
            float t8[8];
#pragma unroll
            for (int i = 0; i < 8; ++i) {
                const float send = (l & 32) ? sc[2*i] : sc[2*i+1];
                const float keep = (l & 32) ? sc[2*i+1] : sc[2*i];
                t8[i] = keep + __shfl_xor(send, 32, 64);
            }
            float t4[4];
#pragma unroll
            for (int i = 0; i < 4; ++i) {
                const float send = (l & 16) ? t8[2*i] : t8[2*i+1];
                const float keep = (l & 16) ? t8[2*i+1] : t8[2*i];
                t4[i] = keep + __shfl_xor(send, 16, 64);
            }
            float t2[2];
#pragma unroll
            for (int i = 0; i < 2; ++i) {
                const float send = (l & 8) ? t4[2*i] : t4[2*i+1];
                const float keep = (l & 8) ? t4[2*i+1] : t4[2*i];
                t2[i] = keep + __shfl_xor(send, 8, 64);
            }
            float t1;
            {
                const float send = (l & 4) ? t2[0] : t2[1];
                const float keep = (l & 4) ? t2[1] : t2[0];
                t1 = keep + __shfl_xor(send, 4, 64);
                t1 += __shfl_xor(t1, 2, 64);
                t1 += __shfl_xor(t1, 1, 64);
            }

            const float sv = SOFF[s];
            const float bu = pa + sv * (pb + sv * (pc + sv * pd));
            const float e  = __expf(2.0f * t1);
            k[s] = (1.0f - 2.0f / (e + 1.0f)) + bu;

            float nxt;
            if (s == 0) {
                nxt = x + dt * (0.2f * k[0]);
            } else if (s == 1) {
                nxt = x + dt * ((3.0f / 40.0f) * k[0] + (9.0f / 40.0f) * k[1]);
            } else if (s == 2) {
                nxt = x + dt * ((44.0f / 45.0f) * k[0] + (-56.0f / 15.0f) * k[1] +
                                (32.0f / 9.0f) * k[2]);
            } else if (s == 3) {
                nxt = x + dt * ((19372.0f / 6561.0f) * k[0] + (-25360.0f / 2187.0f) * k[1] +
                                (64448.0f / 6561.0f) * k[2] + (-212.0f / 729.0f) * k[3]);
            } else if (s == 4) {
                nxt = x + dt * ((9017.0f / 3168.0f) * k[0] + (-355.0f / 33.0f) * k[1] +
                                (46732.0f / 5247.0f) * k[2] + (49.0f / 176.0f) * k[3] +
                                (-5103.0f / 18656.0f) * k[4]);
            } else {
                nxt = x + dt * ((35.0f / 384.0f) * k[0] + (500.0f / 1113.0f) * k[2] +
                                (125.0f / 192.0f) * k[3] + (-2187.0f / 6784.0f) * k[4] +
                                (11.0f / 84.0f) * k[5]);
                x = nxt;
                if ((l & 3) == 0) xs[(n + 1) * NS + r] = nxt;
            }

            if ((l & 3) == 0) {
                const unsigned sidx = (unsigned)(gs + 1) & 1u;   // slot parity by stage
                if (fast) {
                    // own value into LDS (local 128 bypass global) +
                    // line-spread fire-and-forget publish for the peers
                    xb[sidx][r] = nxt;
                    const unsigned long long pv =
                        ((unsigned long long)((unsigned)(gs + 1) + n32) << 32) |
                        (unsigned long long)__float_as_uint(nxt);
                    st_pub_nw(g_tags + (sidx * 512u + (unsigned)r) * 8u, pv);
                } else {
                    const unsigned long long pv =
                        ((unsigned long long)(unsigned)(gs + 1) << 32) |
                        (unsigned long long)__float_as_uint(nxt);
                    __hip_atomic_store(XX + sidx * NS + r, pv, __ATOMIC_RELAXED,
                                       __HIP_MEMORY_SCOPE_AGENT);
                }
            }
        }
    }

    // workers done: release the heater blocks (idempotent, all 4 write)
    if (tid == 0)
        __hip_atomic_store(&XX[W_DONE], DONEV, __ATOMIC_RELAXED,
                           __HIP_MEMORY_SCOPE_AGENT);

    // keep hz alive (never true at runtime; compiler can't prove it)
    if (hz0 + hz1 + hz2 + hz3 == 123.4567f)
        ((float*)XX)[8 * W_SINK] = hz0;
}

__global__ __launch_bounds__(256, 1)
void flow_ys(const float* __restrict__ xs,  // (4096, 512)
             const float* __restrict__ C,   // (16, 512)
             float* __restrict__ ys)        // (4096, 16)
{
    const int step = blockIdx.x;
    const int lane = threadIdx.x & 63;
    const int wv   = threadIdx.x >> 6;  // 0..3
    const float* xrow = xs + step * NS;

#pragma unroll
    for (int oo = 0; oo < 4; ++oo) {
        const int o = (wv << 2) + oo;
        float p = 0.0f;
#pragma unroll
        for (int j = 0; j < 8; ++j)
            p += C[o * NS + lane + 64 * j] * xrow[lane + 64 * j];
#pragma unroll
        for (int m = 1; m < 64; m <<= 1) p += __shfl_xor(p, m, 64);
        if (lane == 0) ys[step * NO + o] = p;
    }
}

extern "C" void kernel_launch(void* const* d_in, const int* in_sizes, int n_in,
                              void* d_out, int out_size, void* d_ws, size_t ws_size,
                              hipStream_t stream) {
    const float* x0 = (const float*)d_in[0];
    const float* t  = (const float*)d_in[1];
    const float* uc = (const float*)d_in[2];
    const float* A  = (const float*)d_in[3];
    const float* B  = (const float*)d_in[4];
    const float* C  = (const float*)d_in[5];

    float* xs = (float*)d_out;            // 4096*512
    float* ys = xs + TT * NS;             // 4096*16
    unsigned long long* XX = (unsigned long long*)d_ws;  // < 11 KB used

    flow_main<<<NBLK_TOT, TPB, 0, stream>>>(x0, t, uc, A, B, xs, XX);
    flow_ys<<<TT, 256, 0, stream>>>(xs, C, ys);
}

// Round 13
// 55490.240 us; speedup vs baseline: 5.6766x; 1.9096x over previous
//
#include <hip/hip_runtime.h>
#include <math.h>

#define NS 512          // states
#define NI 32           // inputs
#define NO 16           // outputs
#define TT 4096         // time points
#define NSTEP (TT - 1)  // 4095 integration steps
#define TPB 512
#define NBLK_TOT 64     // launched blocks; 4 co-XCD blocks win the election
#define GK 4            // group size. R11 PROVED GK=4 is the register-topology
                        // optimum (256KB A/CU = half RF). GK=2 spills (315ms).

// ---- control plane: d_ws (re-poisoned each iteration; agent-scope proven) ----
#define W_CNT   1024
#define W_WIN   1200
#define W_DEC   1280
#define W_SINK  1320
#define W_DONE  1336
#define W_NONCE 1352
#define POISON64 0xAAAAAAAAAAAAAAAAull
#define H1V 0x1111000011110001ull
#define H2V 0x2222000022220002ull
#define DONEV 0x600D600D600D600Dull
#define CAP_ELECT  10000000ll    // 0.1 s @ 100 MHz s_memrealtime
#define CAP_HAND    1000000ll    // 10 ms
#define CAP_DEC    50000000ll    // 0.5 s
#define CAP_POLL   30000000ll    // 0.3 s failsafe
#define CAP_HEAT   30000000ll    // 0.3 s failsafe for heater blocks

// ---- data plane: module-scope device global (coarse VRAM). ----
// Primitive matrix (R0-R12): plain load = stale L1; sc0/nt load = MALL;
// atomic add0 = the only L2-served read; publish = unscoped atomic swap
// (TCC-executed, L2-resident, fire-and-forget safe). R10 = 48.1ms (GK=4,
// line-spread tags, own-block LDS bypass, sliced detection). R12's
// in-poll-loop FMA overlap REGRESSED (106ms): anything inserted in the
// detect loop multiplies across sweeps — keep it tight.
// R13: 2-DEEP PIPELINED POLL — two polls in flight, s_waitcnt vmcnt(1)
// alternation (older poll guaranteed complete; "+v" pins the check after
// the wait). Poll period RTT -> RTT/2, loop body stays 3 instructions.
// Beacon moved off the detect critical path (absorbed by flag-wait).
//   word idx: row i of slot par lives at g_tags[(par*512 + i)*8] (line-spread)
//   hello words at g_tags[8192 + s*16]
__device__ unsigned long long g_tags[8192 + 64];
#define G_HELLO 8192

__device__ __forceinline__ long long rt() {
    return (long long)__builtin_amdgcn_s_memrealtime();
}

// publish + wait (handshake only)
__device__ __forceinline__ void st_pub(unsigned long long* p, unsigned long long v) {
    asm volatile("global_atomic_swap_x2 %0, %1, off\n\ts_waitcnt vmcnt(0)"
                 :: "v"(p), "v"(v) : "memory");
}

// publish fire-and-forget (data plane): swap is atomic 8B, self-ordering
__device__ __forceinline__ void st_pub_nw(unsigned long long* p, unsigned long long v) {
    asm volatile("global_atomic_swap_x2 %0, %1, off"
                 :: "v"(p), "v"(v) : "memory");
}

// read via atomic add-0 (sc0 = return old) -> L2-served (R5-proven)
__device__ __forceinline__ unsigned long long ld_atom(const unsigned long long* p) {
    unsigned long long v;
    const unsigned long long z = 0;
    asm volatile("global_atomic_add_x2 %0, %1, %2, off sc0\n\ts_waitcnt vmcnt(0)"
                 : "=&v"(v) : "v"(p), "v"(z) : "memory");
    return v;
}

__global__ __launch_bounds__(TPB, 2)
void flow_main(const float* __restrict__ x0,
               const float* __restrict__ tt,
               const float* __restrict__ uc,   // (4, 4095, 32): d,c,b,a
               const float* __restrict__ A,    // (512, 512)
               const float* __restrict__ B,    // (512, 32)
               float* __restrict__ xs,         // (4096, 512)
               unsigned long long* __restrict__ XX)
{
    const int tid = threadIdx.x;
    __shared__ int s_sb, s_mode;     // 0=heater, 1=FAST(L2 atomics), 2=SLOW(agent)
    __shared__ unsigned s_n32;       // per-run tag nonce (FAST)
    __shared__ float xb[2][NS];      // LDS exchange buffers (FAST mode)
    __shared__ int wflag[8];         // per-wave stage flags (release/acquire)

    if (tid == 0) {
        s_n32 = 0;
#pragma unroll
        for (int i = 0; i < 8; ++i) wflag[i] = -1;
        unsigned xcc;
        asm volatile("s_getreg_b32 %0, hwreg(HW_REG_XCC_ID)" : "=s"(xcc));
        xcc &= 7u;

        const unsigned long long old = __hip_atomic_fetch_add(
            &XX[W_CNT + (int)xcc * 16], 1ull,
            __ATOMIC_RELAXED, __HIP_MEMORY_SCOPE_AGENT);
        const int slot = (int)(unsigned)(old - POISON64);
        if (slot == GK - 1) {
            unsigned long long exp = POISON64;
            __hip_atomic_compare_exchange_strong(
                &XX[W_WIN], &exp, (unsigned long long)xcc,
                __ATOMIC_RELAXED, __ATOMIC_RELAXED, __HIP_MEMORY_SCOPE_AGENT);
        }
        long long t0 = rt();
        unsigned long long wv;
        for (;;) {
            wv = __hip_atomic_load(&XX[W_WIN], __ATOMIC_RELAXED,
                                   __HIP_MEMORY_SCOPE_AGENT);
            if (wv != POISON64) break;
            if (rt() - t0 > CAP_ELECT) break;
        }

        int mode = 0, sb = slot;
        if (wv == POISON64) {
            sb = blockIdx.x;                       // unreachable failsafe
            mode = (blockIdx.x < GK) ? 2 : 0;
        } else if ((unsigned long long)xcc == wv && slot < GK) {
            // -- distribute per-run nonce over the PROVEN d_ws control plane --
            unsigned long long nonce = POISON64;
            if (slot == 0) {
                nonce = ((unsigned long long)rt() << 1) | 1ull;  // odd != POISON64
                __hip_atomic_store(&XX[W_NONCE], nonce,
                                   __ATOMIC_RELAXED, __HIP_MEMORY_SCOPE_AGENT);
            } else {
                long long tn = rt();
                for (;;) {
                    nonce = __hip_atomic_load(&XX[W_NONCE], __ATOMIC_RELAXED,
                                              __HIP_MEMORY_SCOPE_AGENT);
                    if (nonce != POISON64) break;
                    if (rt() - tn > CAP_HAND) break;
                }
            }
            if (nonce == POISON64) {
                mode = 2;   // control-plane hiccup: proven SLOW path
            } else {
                // -- two-phase handshake over the exact FAST primitive pair --
                const unsigned long long H1 = H1V ^ nonce, H2 = H2V ^ nonce;
                unsigned long long* hme = &g_tags[G_HELLO + slot * 16];
                st_pub(hme, H1);
                if (slot == 0) {
                    bool ok = true;
                    long long th = rt();
                    for (int i = 1; i < GK && ok; ++i)
                        for (;;) {
                            const unsigned long long h = ld_atom(&g_tags[G_HELLO + i * 16]);
                            if (h == H1 || h == H2) break;
                            if (rt() - th > CAP_HAND) { ok = false; break; }
                        }
                    st_pub(hme, H2);
                    th = rt();
                    for (int i = 1; i < GK && ok; ++i)
                        for (;;) {
                            const unsigned long long h = ld_atom(&g_tags[G_HELLO + i * 16]);
                            if (h == H2) break;
                            if (rt() - th > CAP_HAND) { ok = false; break; }
                        }
                    __hip_atomic_store(&XX[W_DEC], ok ? 1ull : 2ull,
                                       __ATOMIC_RELAXED, __HIP_MEMORY_SCOPE_AGENT);
                    mode = ok ? 1 : 2;
                } else {
                    long long th = rt();
                    for (;;) {
                        const unsigned long long h = ld_atom(&g_tags[G_HELLO + 0]);
                        if (h == H2) break;
                        if (rt() - th > CAP_HAND) break;
                    }
                    st_pub(hme, H2);
                    th = rt();
                    unsigned long long dv;
                    for (;;) {
                        dv = __hip_atomic_load(&XX[W_DEC], __ATOMIC_RELAXED,
                                               __HIP_MEMORY_SCOPE_AGENT);
                        if (dv != POISON64) break;
                        if (rt() - th > CAP_DEC) { dv = 2ull; break; }
                    }
                    mode = (dv == 1ull) ? 1 : 2;
                }
                s_n32 = (unsigned)nonce;
            }
        }
        s_sb = sb; s_mode = mode;
    }
    __syncthreads();
    const int mode = s_mode;
    const int sb   = s_sb;
    const unsigned n32 = s_n32;

    if (mode == 0) {
        // HEATER blocks (R2: proven clock not parked; kept as controlled var)
        float h0 = (float)tid * 1e-6f + 0.05f;
        float h1 = h0 + 0.17f, h2 = h0 + 0.39f, h3 = h0 + 0.71f;
        const long long t0 = rt();
        for (;;) {
            for (int ot = 0; ot < 64; ++ot) {
#pragma unroll
                for (int it = 0; it < 128; ++it) {
                    h0 = fmaf(h0, 0.9999999f, 1e-7f);
                    h1 = fmaf(h1, 0.9999998f, 2e-7f);
                    h2 = fmaf(h2, 0.9999997f, 3e-7f);
                    h3 = fmaf(h3, 0.9999996f, 4e-7f);
                }
            }
            if (__hip_atomic_load(&XX[W_DONE], __ATOMIC_RELAXED,
                                  __HIP_MEMORY_SCOPE_AGENT) == DONEV) break;
            if (rt() - t0 > CAP_HEAT) break;
        }
        if (h0 + h1 + h2 + h3 == 123.4567f)   // never true; keeps hz alive
            ((float*)XX)[8 * W_SINK] = h0;
        return;
    }
    const bool fast = (mode == 1);

    // ---- integrator (R10 layout + R13 pipelined poll) ----
    const int l = tid & 63;
    const int w = tid >> 6;                         // wave 0..7
    const int rloc = ((l >> 5) & 1) | (((l >> 4) & 1) << 1)
                   | (((l >> 3) & 1) << 2) | (((l >> 2) & 1) << 3);
    const int rbase = sb * 128 + w * 16;
    const int r     = rbase + rloc;                 // my quad's row
    const int ch0   = (l & 3) * 8;                  // my 8 B/uc channels
    const int sl    = w * 64 + l;                   // my detection-slice word
    const bool slice_foreign = ((w >> 1) != sb);    // whole-wave uniform

    const float dt = tt[1] - tt[0];

    float a[16][8];                                 // A[rbase+i][j*64+l]
#pragma unroll
    for (int i = 0; i < 16; ++i)
#pragma unroll
        for (int j = 0; j < 8; ++j)
            a[i][j] = A[(rbase + i) * NS + j * 64 + l];

    float B8[8];
    {
        const float4 b0 = *(const float4*)&B[r * NI + ch0];
        const float4 b1 = *(const float4*)&B[r * NI + ch0 + 4];
        B8[0] = b0.x; B8[1] = b0.y; B8[2] = b0.z; B8[3] = b0.w;
        B8[4] = b1.x; B8[5] = b1.y; B8[6] = b1.z; B8[7] = b1.w;
    }

    float x = x0[r];
    float xv[8];
#pragma unroll
    for (int j = 0; j < 8; ++j) xv[j] = x0[j * 64 + l];
    if ((l & 3) == 0) xs[r] = x;

    // heater state (kept live via sink)
    float hz0 = (float)(tid) * 1e-6f + 0.1f;
    float hz1 = hz0 + 0.3f, hz2 = hz0 + 0.7f, hz3 = hz0 + 1.1f;

    const float SOFF[6] = {0.0f, 0.2f * dt, 0.3f * dt, 0.8f * dt,
                           (8.0f / 9.0f) * dt, dt};
    float k[6];
    const long long tstart = rt();

    for (int n = 0; n < NSTEP; ++n) {
        const float* un = uc + n * NI + ch0;
        float pq[4];
#pragma unroll
        for (int qq = 0; qq < 4; ++qq) {
            const float4 v0 = *(const float4*)(un + qq * (NSTEP * NI));
            const float4 v1 = *(const float4*)(un + qq * (NSTEP * NI) + 4);
            float s0 = B8[0]*v0.x + B8[1]*v0.y + B8[2]*v0.z + B8[3]*v0.w
                     + B8[4]*v1.x + B8[5]*v1.y + B8[6]*v1.z + B8[7]*v1.w;
            s0 += __shfl_xor(s0, 1, 64);
            s0 += __shfl_xor(s0, 2, 64);
            pq[qq] = s0;
        }
        const float pd = pq[0], pc = pq[1], pb = pq[2], pa = pq[3];

#pragma unroll
        for (int s = 0; s < 6; ++s) {
            const int gs = n * 6 + s;

            if (gs != 0) {
                if (fast) {
                    const unsigned par = (unsigned)gs & 1u;
                    const unsigned g = (unsigned)gs + n32;
                    if (slice_foreign) {
                        // ---- 2-deep pipelined sliced detection ----
                        // two polls in flight; vmcnt(1) => the OLDER one is
                        // complete ("+v" pins the check after the wait).
                        // Loop body stays 3 instructions (R12 lesson).
                        const unsigned long long* p =
                            g_tags + (par * 512u + (unsigned)sl) * 8u;
                        const unsigned long long z = 0;
                        unsigned long long vA, vB;
                        bool done = false;
                        float myval = 0.0f;
                        asm volatile("global_atomic_add_x2 %0, %1, %2, off sc0"
                                     : "=&v"(vA) : "v"(p), "v"(z) : "memory");
                        asm volatile("global_atomic_add_x2 %0, %1, %2, off sc0"
                                     : "=&v"(vB) : "v"(p), "v"(z) : "memory");
                        unsigned sweep = 0;
                        for (;;) {
                            asm volatile("s_waitcnt vmcnt(1)"
                                         : "+v"(vA) :: "memory");
                            if (!done && (unsigned)(vA >> 32) == g) {
                                myval = __uint_as_float((unsigned)vA);
                                done = true;
                            }
                            if (__all(done)) break;
                            asm volatile("global_atomic_add_x2 %0, %1, %2, off sc0"
                                         : "=&v"(vA) : "v"(p), "v"(z) : "memory");
                            asm volatile("s_waitcnt vmcnt(1)"
                                         : "+v"(vB) :: "memory");
                            if (!done && (unsigned)(vB >> 32) == g) {
                                myval = __uint_as_float((unsigned)vB);
                                done = true;
                            }
                            if (__all(done)) break;
                            asm volatile("global_atomic_add_x2 %0, %1, %2, off sc0"
                                         : "=&v"(vB) : "v"(p), "v"(z) : "memory");
                            if (((++sweep) & 0xFFu) == 0 &&
                                rt() - tstart > CAP_POLL)
                                return;
                        }
                        xb[par][sl] = myval;
                    }
                    // own-slice waves: own 128 arrived via writers' LDS
                    // stores (end of stage gs-1, before their flag release)
                    if (l == 0)
                        __hip_atomic_store(&wflag[w], gs, __ATOMIC_RELEASE,
                                           __HIP_MEMORY_SCOPE_WORKGROUP);
                    if (w == 0) {
                        // FAST beacon (mode telemetry): 32-way LDS conflict
                        // read, placed AFTER flag release so the flag-wait
                        // absorbs its cost (off the detect critical path)
                        unsigned bdum;
                        const unsigned baddr = ((l & 31) << 7) | ((l >> 5) << 2);
                        asm volatile("ds_read_b32 %0, %1\n\ts_waitcnt lgkmcnt(0)"
                                     : "=v"(bdum) : "v"(baddr));
                    }
                    // wait for all 8 waves (lane i checks flag i&7)
                    unsigned fsw = 0;
                    for (;;) {
                        const int m = __hip_atomic_load(
                            &wflag[l & 7], __ATOMIC_ACQUIRE,
                            __HIP_MEMORY_SCOPE_WORKGROUP);
                        if (__all(m >= gs)) break;
                        if (((++fsw) & 0x3FFFu) == 0 &&
                            rt() - tstart > CAP_POLL)
                            return;
                    }
                    // drain the leftover pipelined poll (completed long ago
                    // by now -> ~free; guards VGPR reuse next stage)
                    asm volatile("s_waitcnt vmcnt(0)" ::: "memory");
#pragma unroll
                    for (int j = 0; j < 8; ++j)
                        xv[j] = xb[par][j * 64 + l];
                } else {
                    // SLOW: proven agent-scope poll over d_ws (all waves)
                    unsigned long long* p =
                        (unsigned long long*)XX + ((unsigned)gs & 1u) * NS + l;
                    unsigned done = 0, sweep = 0;
                    unsigned long long v[8];
                    while (done != 0xFFu) {
#pragma unroll
                        for (int j = 0; j < 8; ++j)
                            if (!(done & (1u << j)))
                                v[j] = __hip_atomic_load(
                                    p + 64 * j, __ATOMIC_RELAXED,
                                    __HIP_MEMORY_SCOPE_AGENT);
#pragma unroll
                        for (int j = 0; j < 8; ++j) {
                            if (!(done & (1u << j))) {
                                if (__all((unsigned)(v[j] >> 32) == (unsigned)gs)) {
                                    xv[j] = __uint_as_float((unsigned)v[j]);
                                    done |= (1u << j);
                                }
                            }
                        }
                        if (((++sweep) & 0xFFFu) == 0 &&
                            rt() - tstart > CAP_POLL)
                            return;
                    }
                }
            }

            float sc[16];
#pragma unroll
            for (int i = 0; i < 16; ++i) sc[i] = 0.0f;
#pragma unroll
            for (int j = 0; j < 8; ++j)
#pragma unroll
                for (int i = 0; i < 16; ++i)
                    sc[i] = fmaf(a[i][j], xv[j], sc[i]);

            // pack-butterfly: 16 row sums over 64 lanes
            float t8[8];
#pragma unroll
            for (int i = 0; i < 8; ++i) {
                const float send = (l & 32) ? sc[2*i] : sc[2*i+1];
                const float keep = (l & 32) ? sc[2*i+1] : sc[2*i];
                t8[i] = keep + __shfl_xor(send, 32, 64);
            }
            float t4[4];
#pragma unroll
            for (int i = 0; i < 4; ++i) {
                const float send = (l & 16) ? t8[2*i] : t8[2*i+1];
                const float keep = (l & 16) ? t8[2*i+1] : t8[2*i];
                t4[i] = keep + __shfl_xor(send, 16, 64);
            }
            float t2[2];
#pragma unroll
            for (int i = 0; i < 2; ++i) {
                const float send = (l & 8) ? t4[2*i] : t4[2*i+1];
                const float keep = (l & 8) ? t4[2*i+1] : t4[2*i];
                t2[i] = keep + __shfl_xor(send, 8, 64);
            }
            float t1;
            {
                const float send = (l & 4) ? t2[0] : t2[1];
                const float keep = (l & 4) ? t2[1] : t2[0];
                t1 = keep + __shfl_xor(send, 4, 64);
                t1 += __shfl_xor(t1, 2, 64);
                t1 += __shfl_xor(t1, 1, 64);
            }

            const float sv = SOFF[s];
            const float bu = pa + sv * (pb + sv * (pc + sv * pd));
            const float e  = __expf(2.0f * t1);
            k[s] = (1.0f - 2.0f / (e + 1.0f)) + bu;

            float nxt;
            if (s == 0) {
                nxt = x + dt * (0.2f * k[0]);
            } else if (s == 1) {
                nxt = x + dt * ((3.0f / 40.0f) * k[0] + (9.0f / 40.0f) * k[1]);
            } else if (s == 2) {
                nxt = x + dt * ((44.0f / 45.0f) * k[0] + (-56.0f / 15.0f) * k[1] +
                                (32.0f / 9.0f) * k[2]);
            } else if (s == 3) {
                nxt = x + dt * ((19372.0f / 6561.0f) * k[0] + (-25360.0f / 2187.0f) * k[1] +
                                (64448.0f / 6561.0f) * k[2] + (-212.0f / 729.0f) * k[3]);
            } else if (s == 4) {
                nxt = x + dt * ((9017.0f / 3168.0f) * k[0] + (-355.0f / 33.0f) * k[1] +
                                (46732.0f / 5247.0f) * k[2] + (49.0f / 176.0f) * k[3] +
                                (-5103.0f / 18656.0f) * k[4]);
            } else {
                nxt = x + dt * ((35.0f / 384.0f) * k[0] + (500.0f / 1113.0f) * k[2] +
                                (125.0f / 192.0f) * k[3] + (-2187.0f / 6784.0f) * k[4] +
                                (11.0f / 84.0f) * k[5]);
                x = nxt;
                if ((l & 3) == 0) xs[(n + 1) * NS + r] = nxt;
            }

            if ((l & 3) == 0) {
                const unsigned sidx = (unsigned)(gs + 1) & 1u;   // slot parity by stage
                if (fast) {
                    // own value into LDS (local 128 bypass global) +
                    // line-spread fire-and-forget publish for the peers
                    xb[sidx][r] = nxt;
                    const unsigned long long pv =
                        ((unsigned long long)((unsigned)(gs + 1) + n32) << 32) |
                        (unsigned long long)__float_as_uint(nxt);
                    st_pub_nw(g_tags + (sidx * 512u + (unsigned)r) * 8u, pv);
                } else {
                    const unsigned long long pv =
                        ((unsigned long long)(unsigned)(gs + 1) << 32) |
                        (unsigned long long)__float_as_uint(nxt);
                    __hip_atomic_store(XX + sidx * NS + r, pv, __ATOMIC_RELAXED,
                                       __HIP_MEMORY_SCOPE_AGENT);
                }
            }
        }
    }

    // workers done: release the heater blocks (idempotent, all 4 write)
    if (tid == 0)
        __hip_atomic_store(&XX[W_DONE], DONEV, __ATOMIC_RELAXED,
                           __HIP_MEMORY_SCOPE_AGENT);

    // keep hz alive (never true at runtime; compiler can't prove it)
    if (hz0 + hz1 + hz2 + hz3 == 123.4567f)
        ((float*)XX)[8 * W_SINK] = hz0;
}

__global__ __launch_bounds__(256, 1)
void flow_ys(const float* __restrict__ xs,  // (4096, 512)
             const float* __restrict__ C,   // (16, 512)
             float* __restrict__ ys)        // (4096, 16)
{
    const int step = blockIdx.x;
    const int lane = threadIdx.x & 63;
    const int wv   = threadIdx.x >> 6;  // 0..3
    const float* xrow = xs + step * NS;

#pragma unroll
    for (int oo = 0; oo < 4; ++oo) {
        const int o = (wv << 2) + oo;
        float p = 0.0f;
#pragma unroll
        for (int j = 0; j < 8; ++j)
            p += C[o * NS + lane + 64 * j] * xrow[lane + 64 * j];
#pragma unroll
        for (int m = 1; m < 64; m <<= 1) p += __shfl_xor(p, m, 64);
        if (lane == 0) ys[step * NO + o] = p;
    }
}

extern "C" void kernel_launch(void* const* d_in, const int* in_sizes, int n_in,
                              void* d_out, int out_size, void* d_ws, size_t ws_size,
                              hipStream_t stream) {
    const float* x0 = (const float*)d_in[0];
    const float* t  = (const float*)d_in[1];
    const float* uc = (const float*)d_in[2];
    const float* A  = (const float*)d_in[3];
    const float* B  = (const float*)d_in[4];
    const float* C  = (const float*)d_in[5];

    float* xs = (float*)d_out;            // 4096*512
    float* ys = xs + TT * NS;             // 4096*16
    unsigned long long* XX = (unsigned long long*)d_ws;  // < 11 KB used

    flow_main<<<NBLK_TOT, TPB, 0, stream>>>(x0, t, uc, A, B, xs, XX);
    flow_ys<<<TT, 256, 0, stream>>>(xs, C, ys);
}

// Round 14
// 44710.349 us; speedup vs baseline: 7.0452x; 1.2411x over previous
//
#include <hip/hip_runtime.h>
#include <math.h>

#define NS 512          // states
#define NI 32           // inputs
#define NO 16           // outputs
#define TT 4096         // time points
#define NSTEP (TT - 1)  // 4095 integration steps
#define TPB 512
#define NBLK_TOT 64     // launched blocks; 4 co-XCD blocks win the election
#define GK 4            // group size. R11 PROVED GK=4 is the register-topology
                        // optimum (256KB A/CU = half RF). GK=2 spills (315ms).

// ---- control plane: d_ws (re-poisoned each iteration; agent-scope proven) ----
#define W_CNT   1024
#define W_WIN   1200
#define W_DEC   1280
#define W_SINK  1320
#define W_DONE  1336
#define W_NONCE 1352
#define POISON64 0xAAAAAAAAAAAAAAAAull
#define H1V 0x1111000011110001ull
#define H2V 0x2222000022220002ull
#define DONEV 0x600D600D600D600Dull
#define CAP_ELECT  10000000ll    // 0.1 s @ 100 MHz s_memrealtime
#define CAP_HAND    1000000ll    // 10 ms
#define CAP_DEC    50000000ll    // 0.5 s
#define CAP_POLL   30000000ll    // 0.3 s failsafe
#define CAP_HEAT   30000000ll    // 0.3 s failsafe for heater blocks

// ---- data plane: module-scope device global (coarse VRAM). ----
// Primitive matrix (R0-R13): plain load = stale L1; sc0/nt load = MALL;
// atomic add0 = the only L2-served read; publish = unscoped atomic swap
// (TCC-executed, L2-resident, fire-and-forget safe).
// Poll-traffic law (R5 870MB/51.5 -> R8 620MB/49.6 -> R13 2.9GB/55.5):
// poll RMWs occupy the same TCC pipeline as publishes — one-outstanding
// polling (R10, 48.1ms) is the cadence optimum; faster polling regresses.
// R14: replace the per-wave LDS flag wait (~150-300cy of LDS round-trips
// re-implementing a barrier in software) with hardware __syncthreads().
// Everything else is R10 verbatim.
//   word idx: row i of slot par lives at g_tags[(par*512 + i)*8] (line-spread)
//   hello words at g_tags[8192 + s*16]
__device__ unsigned long long g_tags[8192 + 64];
#define G_HELLO 8192

__device__ __forceinline__ long long rt() {
    return (long long)__builtin_amdgcn_s_memrealtime();
}

// publish + wait (handshake only)
__device__ __forceinline__ void st_pub(unsigned long long* p, unsigned long long v) {
    asm volatile("global_atomic_swap_x2 %0, %1, off\n\ts_waitcnt vmcnt(0)"
                 :: "v"(p), "v"(v) : "memory");
}

// publish fire-and-forget (data plane): swap is atomic 8B, self-ordering
__device__ __forceinline__ void st_pub_nw(unsigned long long* p, unsigned long long v) {
    asm volatile("global_atomic_swap_x2 %0, %1, off"
                 :: "v"(p), "v"(v) : "memory");
}

// read via atomic add-0 (sc0 = return old) -> L2-served (R5-proven)
__device__ __forceinline__ unsigned long long ld_atom(const unsigned long long* p) {
    unsigned long long v;
    const unsigned long long z = 0;
    asm volatile("global_atomic_add_x2 %0, %1, %2, off sc0\n\ts_waitcnt vmcnt(0)"
                 : "=&v"(v) : "v"(p), "v"(z) : "memory");
    return v;
}

__global__ __launch_bounds__(TPB, 2)
void flow_main(const float* __restrict__ x0,
               const float* __restrict__ tt,
               const float* __restrict__ uc,   // (4, 4095, 32): d,c,b,a
               const float* __restrict__ A,    // (512, 512)
               const float* __restrict__ B,    // (512, 32)
               float* __restrict__ xs,         // (4096, 512)
               unsigned long long* __restrict__ XX)
{
    const int tid = threadIdx.x;
    __shared__ int s_sb, s_mode;     // 0=heater, 1=FAST(L2 atomics), 2=SLOW(agent)
    __shared__ unsigned s_n32;       // per-run tag nonce (FAST)
    __shared__ float xb[2][NS];      // LDS exchange buffers (FAST mode)
    __shared__ int s_abort;          // collective-exit flag (failsafe only)

    if (tid == 0) {
        s_n32 = 0; s_abort = 0;
        unsigned xcc;
        asm volatile("s_getreg_b32 %0, hwreg(HW_REG_XCC_ID)" : "=s"(xcc));
        xcc &= 7u;

        const unsigned long long old = __hip_atomic_fetch_add(
            &XX[W_CNT + (int)xcc * 16], 1ull,
            __ATOMIC_RELAXED, __HIP_MEMORY_SCOPE_AGENT);
        const int slot = (int)(unsigned)(old - POISON64);
        if (slot == GK - 1) {
            unsigned long long exp = POISON64;
            __hip_atomic_compare_exchange_strong(
                &XX[W_WIN], &exp, (unsigned long long)xcc,
                __ATOMIC_RELAXED, __ATOMIC_RELAXED, __HIP_MEMORY_SCOPE_AGENT);
        }
        long long t0 = rt();
        unsigned long long wv;
        for (;;) {
            wv = __hip_atomic_load(&XX[W_WIN], __ATOMIC_RELAXED,
                                   __HIP_MEMORY_SCOPE_AGENT);
            if (wv != POISON64) break;
            if (rt() - t0 > CAP_ELECT) break;
        }

        int mode = 0, sb = slot;
        if (wv == POISON64) {
            sb = blockIdx.x;                       // unreachable failsafe
            mode = (blockIdx.x < GK) ? 2 : 0;
        } else if ((unsigned long long)xcc == wv && slot < GK) {
            // -- distribute per-run nonce over the PROVEN d_ws control plane --
            unsigned long long nonce = POISON64;
            if (slot == 0) {
                nonce = ((unsigned long long)rt() << 1) | 1ull;  // odd != POISON64
                __hip_atomic_store(&XX[W_NONCE], nonce,
                                   __ATOMIC_RELAXED, __HIP_MEMORY_SCOPE_AGENT);
            } else {
                long long tn = rt();
                for (;;) {
                    nonce = __hip_atomic_load(&XX[W_NONCE], __ATOMIC_RELAXED,
                                              __HIP_MEMORY_SCOPE_AGENT);
                    if (nonce != POISON64) break;
                    if (rt() - tn > CAP_HAND) break;
                }
            }
            if (nonce == POISON64) {
                mode = 2;   // control-plane hiccup: proven SLOW path
            } else {
                // -- two-phase handshake over the exact FAST primitive pair --
                const unsigned long long H1 = H1V ^ nonce, H2 = H2V ^ nonce;
                unsigned long long* hme = &g_tags[G_HELLO + slot * 16];
                st_pub(hme, H1);
                if (slot == 0) {
                    bool ok = true;
                    long long th = rt();
                    for (int i = 1; i < GK && ok; ++i)
                        for (;;) {
                            const unsigned long long h = ld_atom(&g_tags[G_HELLO + i * 16]);
                            if (h == H1 || h == H2) break;
                            if (rt() - th > CAP_HAND) { ok = false; break; }
                        }
                    st_pub(hme, H2);
                    th = rt();
                    for (int i = 1; i < GK && ok; ++i)
                        for (;;) {
                            const unsigned long long h = ld_atom(&g_tags[G_HELLO + i * 16]);
                            if (h == H2) break;
                            if (rt() - th > CAP_HAND) { ok = false; break; }
                        }
                    __hip_atomic_store(&XX[W_DEC], ok ? 1ull : 2ull,
                                       __ATOMIC_RELAXED, __HIP_MEMORY_SCOPE_AGENT);
                    mode = ok ? 1 : 2;
                } else {
                    long long th = rt();
                    for (;;) {
                        const unsigned long long h = ld_atom(&g_tags[G_HELLO + 0]);
                        if (h == H2) break;
                        if (rt() - th > CAP_HAND) break;
                    }
                    st_pub(hme, H2);
                    th = rt();
                    unsigned long long dv;
                    for (;;) {
                        dv = __hip_atomic_load(&XX[W_DEC], __ATOMIC_RELAXED,
                                               __HIP_MEMORY_SCOPE_AGENT);
                        if (dv != POISON64) break;
                        if (rt() - th > CAP_DEC) { dv = 2ull; break; }
                    }
                    mode = (dv == 1ull) ? 1 : 2;
                }
                s_n32 = (unsigned)nonce;
            }
        }
        s_sb = sb; s_mode = mode;
    }
    __syncthreads();
    const int mode = s_mode;
    const int sb   = s_sb;
    const unsigned n32 = s_n32;

    if (mode == 0) {
        // HEATER blocks (R2: proven clock not parked; kept as controlled var)
        float h0 = (float)tid * 1e-6f + 0.05f;
        float h1 = h0 + 0.17f, h2 = h0 + 0.39f, h3 = h0 + 0.71f;
        const long long t0 = rt();
        for (;;) {
            for (int ot = 0; ot < 64; ++ot) {
#pragma unroll
                for (int it = 0; it < 128; ++it) {
                    h0 = fmaf(h0, 0.9999999f, 1e-7f);
                    h1 = fmaf(h1, 0.9999998f, 2e-7f);
                    h2 = fmaf(h2, 0.9999997f, 3e-7f);
                    h3 = fmaf(h3, 0.9999996f, 4e-7f);
                }
            }
            if (__hip_atomic_load(&XX[W_DONE], __ATOMIC_RELAXED,
                                  __HIP_MEMORY_SCOPE_AGENT) == DONEV) break;
            if (rt() - t0 > CAP_HEAT) break;
        }
        if (h0 + h1 + h2 + h3 == 123.4567f)   // never true; keeps hz alive
            ((float*)XX)[8 * W_SINK] = h0;
        return;
    }
    const bool fast = (mode == 1);

    // ---- integrator (R10 layout + R14 barrier wait) ----
    const int l = tid & 63;
    const int w = tid >> 6;                         // wave 0..7
    const int rloc = ((l >> 5) & 1) | (((l >> 4) & 1) << 1)
                   | (((l >> 3) & 1) << 2) | (((l >> 2) & 1) << 3);
    const int rbase = sb * 128 + w * 16;
    const int r     = rbase + rloc;                 // my quad's row
    const int ch0   = (l & 3) * 8;                  // my 8 B/uc channels
    const int sl    = w * 64 + l;                   // my detection-slice word
    const bool slice_foreign = ((w >> 1) != sb);    // whole-wave uniform

    const float dt = tt[1] - tt[0];

    float a[16][8];                                 // A[rbase+i][j*64+l]
#pragma unroll
    for (int i = 0; i < 16; ++i)
#pragma unroll
        for (int j = 0; j < 8; ++j)
            a[i][j] = A[(rbase + i) * NS + j * 64 + l];

    float B8[8];
    {
        const float4 b0 = *(const float4*)&B[r * NI + ch0];
        const float4 b1 = *(const float4*)&B[r * NI + ch0 + 4];
        B8[0] = b0.x; B8[1] = b0.y; B8[2] = b0.z; B8[3] = b0.w;
        B8[4] = b1.x; B8[5] = b1.y; B8[6] = b1.z; B8[7] = b1.w;
    }

    float x = x0[r];
    float xv[8];
#pragma unroll
    for (int j = 0; j < 8; ++j) xv[j] = x0[j * 64 + l];
    if ((l & 3) == 0) xs[r] = x;

    // heater state (kept live via sink)
    float hz0 = (float)(tid) * 1e-6f + 0.1f;
    float hz1 = hz0 + 0.3f, hz2 = hz0 + 0.7f, hz3 = hz0 + 1.1f;

    const float SOFF[6] = {0.0f, 0.2f * dt, 0.3f * dt, 0.8f * dt,
                           (8.0f / 9.0f) * dt, dt};
    float k[6];
    const long long tstart = rt();

    for (int n = 0; n < NSTEP; ++n) {
        const float* un = uc + n * NI + ch0;
        float pq[4];
#pragma unroll
        for (int qq = 0; qq < 4; ++qq) {
            const float4 v0 = *(const float4*)(un + qq * (NSTEP * NI));
            const float4 v1 = *(const float4*)(un + qq * (NSTEP * NI) + 4);
            float s0 = B8[0]*v0.x + B8[1]*v0.y + B8[2]*v0.z + B8[3]*v0.w
                     + B8[4]*v1.x + B8[5]*v1.y + B8[6]*v1.z + B8[7]*v1.w;
            s0 += __shfl_xor(s0, 1, 64);
            s0 += __shfl_xor(s0, 2, 64);
            pq[qq] = s0;
        }
        const float pd = pq[0], pc = pq[1], pb = pq[2], pa = pq[3];

#pragma unroll
        for (int s = 0; s < 6; ++s) {
            const int gs = n * 6 + s;

            if (gs != 0) {
                if (fast) {
                    const unsigned par = (unsigned)gs & 1u;
                    const unsigned g = (unsigned)gs + n32;
                    if (slice_foreign) {
                        // sliced detection: ONE RMW/lane/sweep, line-spread,
                        // single-outstanding (R13 proved deeper = slower)
                        const unsigned long long* p =
                            g_tags + (par * 512u + (unsigned)sl) * 8u;
                        bool done = false;
                        unsigned long long v = 0;
                        unsigned sweep = 0;
                        for (;;) {
                            if (!done) {
                                v = ld_atom(p);
                                if ((unsigned)(v >> 32) == g) done = true;
                            }
                            if (__all(done)) break;
                            if (((++sweep) & 0x3FFu) == 0) {
                                if (rt() - tstart > CAP_POLL ||
                                    __hip_atomic_load(&s_abort, __ATOMIC_RELAXED,
                                        __HIP_MEMORY_SCOPE_WORKGROUP)) {
                                    __hip_atomic_store(&s_abort, 1, __ATOMIC_RELAXED,
                                        __HIP_MEMORY_SCOPE_WORKGROUP);
                                    return;
                                }
                            }
                        }
                        xb[par][sl] = __uint_as_float((unsigned)v);
                    }
                    if (w == 0) {
                        // FAST beacon (mode telemetry): 32-way LDS conflict
                        // read; cost absorbed by the barrier wait
                        unsigned bdum;
                        const unsigned baddr = ((l & 31) << 7) | ((l >> 5) << 2);
                        asm volatile("ds_read_b32 %0, %1\n\ts_waitcnt lgkmcnt(0)"
                                     : "=v"(bdum) : "v"(baddr));
                    }
                    // hardware barrier replaces the per-wave flag machinery:
                    // slice writes (above) + own-row writes (end of gs-1,
                    // program order per thread) are LDS-visible after it
                    __syncthreads();
#pragma unroll
                    for (int j = 0; j < 8; ++j)
                        xv[j] = xb[par][j * 64 + l];
                } else {
                    // SLOW: proven agent-scope poll over d_ws (all waves)
                    unsigned long long* p =
                        (unsigned long long*)XX + ((unsigned)gs & 1u) * NS + l;
                    unsigned done = 0, sweep = 0;
                    unsigned long long v[8];
                    while (done != 0xFFu) {
#pragma unroll
                        for (int j = 0; j < 8; ++j)
                            if (!(done & (1u << j)))
                                v[j] = __hip_atomic_load(
                                    p + 64 * j, __ATOMIC_RELAXED,
                                    __HIP_MEMORY_SCOPE_AGENT);
#pragma unroll
                        for (int j = 0; j < 8; ++j) {
                            if (!(done & (1u << j))) {
                                if (__all((unsigned)(v[j] >> 32) == (unsigned)gs)) {
                                    xv[j] = __uint_as_float((unsigned)v[j]);
                                    done |= (1u << j);
                                }
                            }
                        }
                        if (((++sweep) & 0xFFFu) == 0 &&
                            rt() - tstart > CAP_POLL)
                            return;
                    }
                }
            }

            float sc[16];
#pragma unroll
            for (int i = 0; i < 16; ++i) sc[i] = 0.0f;
#pragma unroll
            for (int j = 0; j < 8; ++j)
#pragma unroll
                for (int i = 0; i < 16; ++i)
                    sc[i] = fmaf(a[i][j], xv[j], sc[i]);

            // pack-butterfly: 16 row sums over 64 lanes
            float t8[8];
#pragma unroll
            for (int i = 0; i < 8; ++i) {
                const float send = (l & 32) ? sc[2*i] : sc[2*i+1];
                const float keep = (l & 32) ? sc[2*i+1] : sc[2*i];
                t8[i] = keep + __shfl_xor(send, 32, 64);
            }
            float t4[4];
#pragma unroll
            for (int i = 0; i < 4; ++i) {
                const float send = (l & 16) ? t8[2*i] : t8[2*i+1];
                const float keep = (l & 16) ? t8[2*i+1] : t8[2*i];
                t4[i] = keep + __shfl_xor(send, 16, 64);
            }
            float t2[2];
#pragma unroll
            for (int i = 0; i < 2; ++i) {
                const float send = (l & 8) ? t4[2*i] : t4[2*i+1];
                const float keep = (l & 8) ? t4[2*i+1] : t4[2*i];
                t2[i] = keep + __shfl_xor(send, 8, 64);
            }
            float t1;
            {
                const float send = (l & 4) ? t2[0] : t2[1];
                const float keep = (l & 4) ? t2[1] : t2[0];
                t1 = keep + __shfl_xor(send, 4, 64);
                t1 += __shfl_xor(t1, 2, 64);
                t1 += __shfl_xor(t1, 1, 64);
            }

            const float sv = SOFF[s];
            const float bu = pa + sv * (pb + sv * (pc + sv * pd));
            const float e  = __expf(2.0f * t1);
            k[s] = (1.0f - 2.0f / (e + 1.0f)) + bu;

            float nxt;
            if (s == 0) {
                nxt = x + dt * (0.2f * k[0]);
            } else if (s == 1) {
                nxt = x + dt * ((3.0f / 40.0f) * k[0] + (9.0f / 40.0f) * k[1]);
            } else if (s == 2) {
                nxt = x + dt * ((44.0f / 45.0f) * k[0] + (-56.0f / 15.0f) * k[1] +
                                (32.0f / 9.0f) * k[2]);
            } else if (s == 3) {
                nxt = x + dt * ((19372.0f / 6561.0f) * k[0] + (-25360.0f / 2187.0f) * k[1] +
                                (64448.0f / 6561.0f) * k[2] + (-212.0f / 729.0f) * k[3]);
            } else if (s == 4) {
                nxt = x + dt * ((9017.0f / 3168.0f) * k[0] + (-355.0f / 33.0f) * k[1] +
                                (46732.0f / 5247.0f) * k[2] + (49.0f / 176.0f) * k[3] +
                                (-5103.0f / 18656.0f) * k[4]);
            } else {
                nxt = x + dt * ((35.0f / 384.0f) * k[0] + (500.0f / 1113.0f) * k[2] +
                                (125.0f / 192.0f) * k[3] + (-2187.0f / 6784.0f) * k[4] +
                                (11.0f / 84.0f) * k[5]);
                x = nxt;
                if ((l & 3) == 0) xs[(n + 1) * NS + r] = nxt;
            }

            if ((l & 3) == 0) {
                const unsigned sidx = (unsigned)(gs + 1) & 1u;   // slot parity by stage
                if (fast) {
                    // own value into LDS (local 128 bypass global) +
                    // line-spread fire-and-forget publish for the peers
                    xb[sidx][r] = nxt;
                    const unsigned long long pv =
                        ((unsigned long long)((unsigned)(gs + 1) + n32) << 32) |
                        (unsigned long long)__float_as_uint(nxt);
                    st_pub_nw(g_tags + (sidx * 512u + (unsigned)r) * 8u, pv);
                } else {
                    const unsigned long long pv =
                        ((unsigned long long)(unsigned)(gs + 1) << 32) |
                        (unsigned long long)__float_as_uint(nxt);
                    __hip_atomic_store(XX + sidx * NS + r, pv, __ATOMIC_RELAXED,
                                       __HIP_MEMORY_SCOPE_AGENT);
                }
            }
        }
    }

    // workers done: release the heater blocks (idempotent, all 4 write)
    if (tid == 0)
        __hip_atomic_store(&XX[W_DONE], DONEV, __ATOMIC_RELAXED,
                           __HIP_MEMORY_SCOPE_AGENT);

    // keep hz alive (never true at runtime; compiler can't prove it)
    if (hz0 + hz1 + hz2 + hz3 == 123.4567f)
        ((float*)XX)[8 * W_SINK] = hz0;
}

__global__ __launch_bounds__(256, 1)
void flow_ys(const float* __restrict__ xs,  // (4096, 512)
             const float* __restrict__ C,   // (16, 512)
             float* __restrict__ ys)        // (4096, 16)
{
    const int step = blockIdx.x;
    const int lane = threadIdx.x & 63;
    const int wv   = threadIdx.x >> 6;  // 0..3
    const float* xrow = xs + step * NS;

#pragma unroll
    for (int oo = 0; oo < 4; ++oo) {
        const int o = (wv << 2) + oo;
        float p = 0.0f;
#pragma unroll
        for (int j = 0; j < 8; ++j)
            p += C[o * NS + lane + 64 * j] * xrow[lane + 64 * j];
#pragma unroll
        for (int m = 1; m < 64; m <<= 1) p += __shfl_xor(p, m, 64);
        if (lane == 0) ys[step * NO + o] = p;
    }
}

extern "C" void kernel_launch(void* const* d_in, const int* in_sizes, int n_in,
                              void* d_out, int out_size, void* d_ws, size_t ws_size,
                              hipStream_t stream) {
    const float* x0 = (const float*)d_in[0];
    const float* t  = (const float*)d_in[1];
    const float* uc = (const float*)d_in[2];
    const float* A  = (const float*)d_in[3];
    const float* B  = (const float*)d_in[4];
    const float* C  = (const float*)d_in[5];

    float* xs = (float*)d_out;            // 4096*512
    float* ys = xs + TT * NS;             // 4096*16
    unsigned long long* XX = (unsigned long long*)d_ws;  // < 11 KB used

    flow_main<<<NBLK_TOT, TPB, 0, stream>>>(x0, t, uc, A, B, xs, XX);
    flow_ys<<<TT, 256, 0, stream>>>(xs, C, ys);
}